// Round 9
// baseline (430.290 us; speedup 1.0000x reference)
//
#include <hip/hip_runtime.h>

#define N_TEX 65536
#define C 16
#define U 4194304
#define ILP 4
#define MIMIC_REP 4

typedef float    f32x4 __attribute__((ext_vector_type(4)));
typedef int      i32x4 __attribute__((ext_vector_type(4)));
typedef _Float16 f16x4 __attribute__((ext_vector_type(4)));

// ---------------------------------------------------------------------------
// Convert fp32 texture (4 MiB) -> fp16 (2 MiB) in d_ws.
// ---------------------------------------------------------------------------
__global__ __launch_bounds__(256) void convert_kernel(
    const f32x4* __restrict__ in, f16x4* __restrict__ out16)
{
    const int i = blockIdx.x * 256 + threadIdx.x;
    f32x4 v = __builtin_nontemporal_load(&in[i]);
    f16x4 h;
    h.x = (_Float16)v.x; h.y = (_Float16)v.y;
    h.z = (_Float16)v.z; h.w = (_Float16)v.w;
    out16[i] = h;
}

// ---------------------------------------------------------------------------
// Cheap warm kernel (R7 version): 2,048 blocks, XCD-aware, single touch.
// ---------------------------------------------------------------------------
__global__ __launch_bounds__(256) void warm_kernel(
    const i32x4* __restrict__ texv, const f32x4* __restrict__ paramv)
{
    const int b = blockIdx.x;
    const int t = threadIdx.x;
    const int i = t >> 5;
    const int g = t & 31;
    const int s = (b & 7) + 8 * ((b >> 3) * 8 + i);
    const int k0 = g >> 4;
    const int m  = g & 15;
    f32x4 p0 = paramv[s * 16 + m + k0 * 262144];
    f32x4 p1 = paramv[s * 16 + m + (k0 + 2) * 262144];
    const int cbase = (b >> 3) * 512 + t * 2;
    i32x4 t0 = texv[cbase];
    i32x4 t1 = texv[cbase + 1];
    asm volatile("" :: "v"(p0), "v"(p1), "v"(t0), "v"(t1));
}

// ---------------------------------------------------------------------------
// MIMIC diagnostic: the EXACT sampler body repeated MIMIC_REP times so its
// counters rank in the rocprof top-5 (dur > fill's ~154us). Pointers are
// asm-laundered per rep so the compiler re-issues every load/store (no CSE,
// no DSE). Stores go to d_ws scratch. Discriminates:
//   dur ~ 4x45us + small FETCH  -> L2 self-warming works
//   dur ~ 4x78us + small FETCH  -> structural pipe serialization
//   dur ~ 4x78us + huge  FETCH  -> store stream evicts texture/param
// ---------------------------------------------------------------------------
__global__ __launch_bounds__(256) void mimic_kernel(
    const f16x4* __restrict__ tex16, const float* __restrict__ param,
    f32x4* __restrict__ outw)
{
    const int NT  = (U * 4) / ILP;
    const int tid = blockIdx.x * 256 + threadIdx.x;
    const int q   = tid & 3;

    for (int rep = 0; rep < MIMIC_REP; ++rep) {
        unsigned long long tp = (unsigned long long)tex16;
        unsigned long long pp = (unsigned long long)param;
        unsigned long long op = (unsigned long long)outw;
        asm volatile("" : "+v"(tp), "+v"(pp), "+v"(op));
        const f16x4* T = (const f16x4*)tp;
        const float* P = (const float*)pp;
        f32x4*       O = (f32x4*)op;

        float p[ILP];
#pragma unroll
        for (int k = 0; k < ILP; ++k)
            p[k] = __builtin_nontemporal_load(&P[(tid + k * NT) >> 2]);

        float w[ILP];
        f16x4 a[ILP], b[ILP];
#pragma unroll
        for (int k = 0; k < ILP; ++k) {
            const float t = p[k] * (float)(N_TEX - 1);
            float f = fminf(fmaxf(floorf(t), 0.0f), (float)(N_TEX - 1));
            const int i0 = (int)f;
            const int i1 = min(i0 + 1, N_TEX - 1);
            w[k] = t - f;
            a[k] = T[i0 * 4 + q];
            b[k] = T[i1 * 4 + q];
        }

#pragma unroll
        for (int k = 0; k < ILP; ++k) {
            const float wk = w[k], iw = 1.0f - wk;
            f32x4 r;
            r.x = (float)a[k].x * iw + (float)b[k].x * wk;
            r.y = (float)a[k].y * iw + (float)b[k].y * wk;
            r.z = (float)a[k].z * iw + (float)b[k].z * wk;
            r.w = (float)a[k].w * iw + (float)b[k].w * wk;
            __builtin_nontemporal_store(r, &O[tid + k * NT]);
        }
    }
}

// ---------------------------------------------------------------------------
// Real sampler: as R4 but with MAX-strength cache-bypass stores
// (global_store_dwordx4 sc0 sc1 nt) so the 256 MiB output stream does not
// allocate/evict in L2. sc bits are coherence-scope hints: safe for
// correctness, only affects caching.
// ---------------------------------------------------------------------------
__global__ __launch_bounds__(256) void sampler1d_kernel(
    const f16x4* __restrict__ tex16, const float* __restrict__ param,
    f32x4* __restrict__ out)
{
    const int NT  = (U * 4) / ILP;
    const int tid = blockIdx.x * 256 + threadIdx.x;
    const int q   = tid & 3;

    float p[ILP];
#pragma unroll
    for (int k = 0; k < ILP; ++k)
        p[k] = __builtin_nontemporal_load(&param[(tid + k * NT) >> 2]);

    float w[ILP];
    f16x4 a[ILP], b[ILP];
#pragma unroll
    for (int k = 0; k < ILP; ++k) {
        const float t = p[k] * (float)(N_TEX - 1);
        float f = floorf(t);
        f = fminf(fmaxf(f, 0.0f), (float)(N_TEX - 1));
        const int i0 = (int)f;
        const int i1 = min(i0 + 1, N_TEX - 1);
        w[k] = t - f;
        a[k] = tex16[i0 * 4 + q];
        b[k] = tex16[i1 * 4 + q];
    }

#pragma unroll
    for (int k = 0; k < ILP; ++k) {
        const float wk = w[k], iw = 1.0f - wk;
        f32x4 r;
        r.x = (float)a[k].x * iw + (float)b[k].x * wk;
        r.y = (float)a[k].y * iw + (float)b[k].y * wk;
        r.z = (float)a[k].z * iw + (float)b[k].z * wk;
        r.w = (float)a[k].w * iw + (float)b[k].w * wk;
        f32x4* addr = &out[tid + k * NT];
        asm volatile("global_store_dwordx4 %0, %1, off sc0 sc1 nt"
                     :: "v"(addr), "v"(r) : "memory");
    }
}

extern "C" void kernel_launch(void* const* d_in, const int* in_sizes, int n_in,
                              void* d_out, int out_size, void* d_ws, size_t ws_size,
                              hipStream_t stream) {
    const f32x4* tex32 = (const f32x4*)d_in[0];
    const float* param = (const float*)d_in[1];
    f32x4*       out   = (f32x4*)d_out;
    f16x4*       tex16 = (f16x4*)d_ws;                          // 2 MiB
    f32x4*       mimw  = (f32x4*)((char*)d_ws + (4u << 20));    // +256 MiB

    const int total_thr = (U * 4) / ILP;   // 16,384 blocks

    convert_kernel<<<(N_TEX * C / 4) / 256, 256, 0, stream>>>(tex32, tex16);
    warm_kernel<<<2048, 256, 0, stream>>>((const i32x4*)tex16, (const f32x4*)param);

    if (ws_size >= (4ull << 20) + (256ull << 20)) {
        mimic_kernel<<<total_thr / 256, 256, 0, stream>>>(tex16, param, mimw);
    }

    sampler1d_kernel<<<total_thr / 256, 256, 0, stream>>>(tex16, param, out);
}

// Round 10
// 100.842 us; speedup vs baseline: 4.2670x; 4.2670x over previous
//
#include <hip/hip_runtime.h>

#define N_TEX 65536
#define C 16
#define U 4194304
#define ILP 4

typedef float    f32x4 __attribute__((ext_vector_type(4)));
typedef int      i32x4 __attribute__((ext_vector_type(4)));
typedef _Float16 f16x8 __attribute__((ext_vector_type(8)));

// ---------------------------------------------------------------------------
// Build paired-interleaved fp16 texture in d_ws (4 MiB):
//   pairs entry i (64 B, line-aligned) = [a0,b0,a1,b1,...,a15,b15] where
//   a = row i, b = row min(i+1, N-1), channel-interleaved fp16.
// A sample then needs exactly ONE 64 B line; lane q's 16 B chunk is exactly
// its 4 channels of (a,b) pairs -> no cross-lane traffic.
// ---------------------------------------------------------------------------
__global__ __launch_bounds__(256) void build_pairs_kernel(
    const f32x4* __restrict__ in, f16x8* __restrict__ pairs)
{
    const int id = blockIdx.x * 256 + threadIdx.x;  // 0 .. N_TEX*4-1
    const int i  = id >> 2;
    const int q  = id & 3;
    const int ip = min(i + 1, N_TEX - 1);
    const f32x4 a = in[i * 4 + q];
    const f32x4 b = in[ip * 4 + q];
    f16x8 o;
    o[0] = (_Float16)a.x; o[1] = (_Float16)b.x;
    o[2] = (_Float16)a.y; o[3] = (_Float16)b.y;
    o[4] = (_Float16)a.z; o[5] = (_Float16)b.z;
    o[6] = (_Float16)a.w; o[7] = (_Float16)b.w;
    pairs[id] = o;
}

// ---------------------------------------------------------------------------
// Warm kernel, 2048 blocks, XCD-aware (XCD = b%8).
//   - param: single-touch prefetch of exactly the slices the sampler blocks
//     s == b (mod 8) in this block's range will read (stream data: presence
//     is all that matters).
//   - pairs table: 3 touches per line, each rep reading a DIFFERENT 16 KiB
//     chunk (stride-85 rotation, bijective mod 256). R8 bug fixed: re-touches
//     now come from different blocks' L1s, so L2 actually sees multiple
//     references per line (promotion), instead of L1 filtering them.
// ---------------------------------------------------------------------------
__global__ __launch_bounds__(256) void warm_kernel(
    const i32x4* __restrict__ tabv, const f32x4* __restrict__ paramv)
{
    const int b = blockIdx.x;   // 0..2047
    const int t = threadIdx.x;

    // param prefetch (8 KiB per block)
    const int i  = t >> 5;
    const int g  = t & 31;
    const int s  = (b & 7) + 8 * ((b >> 3) * 8 + i);
    const int k0 = g >> 4;
    const int m  = g & 15;
    f32x4 p0 = paramv[s * 16 + m + k0 * 262144];
    f32x4 p1 = paramv[s * 16 + m + (k0 + 2) * 262144];
    asm volatile("" :: "v"(p0), "v"(p1));

    // pairs table: per XCD 256 chunks x 16 KiB = full 4 MiB copy, 3 touches
#pragma unroll
    for (int r = 0; r < 3; ++r) {
        const int c    = ((b >> 3) + r * 85) & 255;   // bijective rotation
        const int base = c * 1024 + t * 4;            // i32x4 units
        i32x4 t0 = tabv[base + 0];
        i32x4 t1 = tabv[base + 1];
        i32x4 t2 = tabv[base + 2];
        i32x4 t3 = tabv[base + 3];
        asm volatile("" :: "v"(t0), "v"(t1), "v"(t2), "v"(t3));
    }
}

// ---------------------------------------------------------------------------
// Sampler: 4 lanes per sample; ONE dwordx4 gather per lane per sample from
// the paired table (one aligned 64 B line per sample, wave-coalesced in
// 4-lane groups). Plain nontemporal stores (no sc0/sc1 scope bits).
// ---------------------------------------------------------------------------
__global__ __launch_bounds__(256) void sampler1d_kernel(
    const f16x8* __restrict__ pairs, const float* __restrict__ param,
    f32x4* __restrict__ out)
{
    const int NT  = (U * 4) / ILP;
    const int tid = blockIdx.x * 256 + threadIdx.x;
    const int q   = tid & 3;

    float p[ILP];
#pragma unroll
    for (int k = 0; k < ILP; ++k)
        p[k] = __builtin_nontemporal_load(&param[(tid + k * NT) >> 2]);

    float w[ILP];
    f16x8 v[ILP];
#pragma unroll
    for (int k = 0; k < ILP; ++k) {
        const float t = p[k] * (float)(N_TEX - 1);
        float f = fminf(fmaxf(floorf(t), 0.0f), (float)(N_TEX - 1));
        w[k] = t - f;
        v[k] = pairs[(int)f * 4 + q];
    }

#pragma unroll
    for (int k = 0; k < ILP; ++k) {
        const float wk = w[k], iw = 1.0f - wk;
        f32x4 r;
        r.x = (float)v[k][0] * iw + (float)v[k][1] * wk;
        r.y = (float)v[k][2] * iw + (float)v[k][3] * wk;
        r.z = (float)v[k][4] * iw + (float)v[k][5] * wk;
        r.w = (float)v[k][6] * iw + (float)v[k][7] * wk;
        __builtin_nontemporal_store(r, &out[tid + k * NT]);
    }
}

extern "C" void kernel_launch(void* const* d_in, const int* in_sizes, int n_in,
                              void* d_out, int out_size, void* d_ws, size_t ws_size,
                              hipStream_t stream) {
    const f32x4* tex32 = (const f32x4*)d_in[0];
    const float* param = (const float*)d_in[1];
    f32x4*       out   = (f32x4*)d_out;
    f16x8*       pairs = (f16x8*)d_ws;     // 4 MiB paired-interleaved texture

    const int total_thr = (U * 4) / ILP;   // 4,194,304 -> 16,384 blocks

    build_pairs_kernel<<<(N_TEX * 4) / 256, 256, 0, stream>>>(tex32, pairs);
    warm_kernel<<<2048, 256, 0, stream>>>((const i32x4*)pairs, (const f32x4*)param);
    sampler1d_kernel<<<total_thr / 256, 256, 0, stream>>>(pairs, param, out);
}

// Round 11
// 91.602 us; speedup vs baseline: 4.6974x; 1.1009x over previous
//
#include <hip/hip_runtime.h>

#define N_TEX 65536
#define C 16
#define U 4194304
#define ILP 4
#define WTEX_REP 12

typedef float    f32x4 __attribute__((ext_vector_type(4)));
typedef int      i32x4 __attribute__((ext_vector_type(4)));
typedef _Float16 f16x4 __attribute__((ext_vector_type(4)));

// ---------------------------------------------------------------------------
// Convert fp32 texture (4 MiB) -> fp16 (2 MiB) in d_ws.  (2 MiB table: fits
// an XCD L2 with room to spare -- R10 proved 4 MiB tables fight the streams.)
// ---------------------------------------------------------------------------
__global__ __launch_bounds__(256) void convert_kernel(
    const f32x4* __restrict__ in, f16x4* __restrict__ out16)
{
    const int i = blockIdx.x * 256 + threadIdx.x;
    f32x4 v = __builtin_nontemporal_load(&in[i]);
    f16x4 h;
    h.x = (_Float16)v.x; h.y = (_Float16)v.y;
    h.z = (_Float16)v.z; h.w = (_Float16)v.w;
    out16[i] = h;
}

// ---------------------------------------------------------------------------
// Warm kernel, 2048 blocks, XCD-aware (XCD = b%8). ONLY change vs R7 (85.7):
// texture warmed with 12 touches per 8 KiB chunk, each touch issued by a
// DIFFERENT block (chunk index rotated by stride 97, bijective mod 256), so
// every touch reaches L2 (not filtered by the toucher's own L1).  Theory:
// RRIP-like L2 replacement promotes multi-referenced lines; promoted texture
// survives the sampler's param/store streams (dose-response: 1 touch -> 85us,
// ~8 -> ~71us, 16 -> ~43us inferred).
//   - param: single-touch prefetch of the exact slices sampler blocks
//     s == b (mod 8) in range read (presence is enough for stream data).
//   - texture: per XCD, 256 chunks x 8 KiB = full 2 MiB, 12 touches each.
//     Cost ~192 MiB of L2-served reads ~ 6 us.
// ---------------------------------------------------------------------------
__global__ __launch_bounds__(256) void warm_kernel(
    const i32x4* __restrict__ texv, const f32x4* __restrict__ paramv)
{
    const int b = blockIdx.x;   // 0..2047
    const int t = threadIdx.x;

    // param prefetch (8 KiB per block, covers all of param across blocks)
    const int i  = t >> 5;
    const int g  = t & 31;
    const int s  = (b & 7) + 8 * ((b >> 3) * 8 + i);
    const int k0 = g >> 4;
    const int m  = g & 15;
    f32x4 p0 = paramv[s * 16 + m + k0 * 262144];
    f32x4 p1 = paramv[s * 16 + m + (k0 + 2) * 262144];
    asm volatile("" :: "v"(p0), "v"(p1));

    // texture: fp16 table = 131072 i32x4 units; chunk = 512 units (8 KiB).
    // Block (b>>3) touches chunk ((b>>3) + r*97) & 255 at rep r -> each chunk
    // is touched by 12 distinct blocks (97 odd -> bijective mod 256).
#pragma unroll
    for (int r = 0; r < WTEX_REP; ++r) {
        const int c    = ((b >> 3) + r * 97) & 255;
        const int base = c * 512 + t * 2;
        i32x4 t0 = texv[base];
        i32x4 t1 = texv[base + 1];
        asm volatile("" :: "v"(t0), "v"(t1));
    }
}

// ---------------------------------------------------------------------------
// Sampler: EXACT R7 kernel (known 85.7 us in this pipeline) -- fp16 texture,
// 4 lanes/sample, ILP=4, nontemporal param loads + output stores.
// ---------------------------------------------------------------------------
__global__ __launch_bounds__(256) void sampler1d_kernel(
    const f16x4* __restrict__ tex16, const float* __restrict__ param,
    f32x4* __restrict__ out)
{
    const int NT  = (U * 4) / ILP;
    const int tid = blockIdx.x * 256 + threadIdx.x;
    const int q   = tid & 3;

    float p[ILP];
#pragma unroll
    for (int k = 0; k < ILP; ++k)
        p[k] = __builtin_nontemporal_load(&param[(tid + k * NT) >> 2]);

    float w[ILP];
    f16x4 a[ILP], b[ILP];
#pragma unroll
    for (int k = 0; k < ILP; ++k) {
        const float t = p[k] * (float)(N_TEX - 1);
        float f = floorf(t);
        f = fminf(fmaxf(f, 0.0f), (float)(N_TEX - 1));
        const int i0 = (int)f;
        const int i1 = min(i0 + 1, N_TEX - 1);
        w[k] = t - f;
        a[k] = tex16[i0 * 4 + q];
        b[k] = tex16[i1 * 4 + q];
    }

#pragma unroll
    for (int k = 0; k < ILP; ++k) {
        const float wk = w[k], iw = 1.0f - wk;
        f32x4 r;
        r.x = (float)a[k].x * iw + (float)b[k].x * wk;
        r.y = (float)a[k].y * iw + (float)b[k].y * wk;
        r.z = (float)a[k].z * iw + (float)b[k].z * wk;
        r.w = (float)a[k].w * iw + (float)b[k].w * wk;
        __builtin_nontemporal_store(r, &out[tid + k * NT]);
    }
}

extern "C" void kernel_launch(void* const* d_in, const int* in_sizes, int n_in,
                              void* d_out, int out_size, void* d_ws, size_t ws_size,
                              hipStream_t stream) {
    const f32x4* tex32 = (const f32x4*)d_in[0];
    const float* param = (const float*)d_in[1];
    f32x4*       out   = (f32x4*)d_out;
    f16x4*       tex16 = (f16x4*)d_ws;     // 2 MiB scratch

    const int total_thr = (U * 4) / ILP;   // 4,194,304 -> 16,384 blocks

    convert_kernel<<<(N_TEX * C / 4) / 256, 256, 0, stream>>>(tex32, tex16);
    warm_kernel<<<2048, 256, 0, stream>>>((const i32x4*)tex16, (const f32x4*)param);
    sampler1d_kernel<<<total_thr / 256, 256, 0, stream>>>(tex16, param, out);
}